// Round 4
// baseline (122.157 us; speedup 1.0000x reference)
//
#include <hip/hip_runtime.h>
#include <math.h>

// Problem constants (fixed by the reference file)
#define NPOINTS   8192
#define NDIM      64
#define TILE      128          // pairwise output tile per block
#define NT2       64           // NPOINTS / TILE
#define NBLK      2080         // NT2*(NT2+1)/2 triangle blocks
#define NPAIR_BLK 8192         // pair-path blocks (4 waves x 16 pairs each = 524288)

// ws dword/float layout:
//  [0, 262144)        W16   : W as bf16, packed 2/dword (8192 rows x 32 dwords)
//  [262144, 270336)   sq    : row squared norms (fp32 exact)
//  [270336, 272416)   partA : per-block partials of sum 1/(1+d2) over a<b  (2080)
//  [272416, 280608)   a1p   : per-block partials of sum pij*log(pij*(64+d2))  (8192)
//  [280608, 288800)   a3p   : per-block partials of sum pij                   (8192)
#define WS_W16   0
#define WS_SQ    262144
#define WS_PARTA 270336
#define WS_A1P   272416
#define WS_A3P   280608

typedef __attribute__((ext_vector_type(8))) short bf16x8;   // 8 bf16 = 4 VGPRs (MFMA A/B frag)
typedef __attribute__((ext_vector_type(4))) float f32x4;    // MFMA C/D frag

__device__ inline unsigned short f2bf(float f) {            // fp32 -> bf16 RNE
    unsigned u = __float_as_uint(f);
    u += 0x7FFFu + ((u >> 16) & 1u);
    return (unsigned short)(u >> 16);
}
__device__ inline float bflo(unsigned u) { return __uint_as_float(u << 16); }
__device__ inline float bfhi(unsigned u) { return __uint_as_float(u & 0xFFFF0000u); }

// One wave per row: exact fp32 row norm + bf16 conversion of W (packed 2/dword).
__global__ __launch_bounds__(256) void prep_kernel(const float* __restrict__ W,
                                                   float* __restrict__ sq,
                                                   unsigned* __restrict__ W16) {
    int wid  = (blockIdx.x * 256 + threadIdx.x) >> 6;   // row
    int lane = threadIdx.x & 63;
    float v = W[wid * NDIM + lane];
    float s = v * v;
    #pragma unroll
    for (int m = 32; m >= 1; m >>= 1) s += __shfl_xor(s, m, 64);
    if (lane == 0) sq[wid] = s;
    unsigned bf   = f2bf(v);
    unsigned peer = (unsigned)__shfl_xor((int)bf, 1, 64);
    if ((lane & 1) == 0)                                 // even lane packs (elem l | elem l+1)
        W16[wid * 32 + (lane >> 1)] = (bf & 0xFFFFu) | (peer << 16);
}

// Fused main kernel. Blocks [0,NBLK): 128x128 MFMA tile of the Cauchy partition
// (triangle only, frags straight from global bf16 — no LDS staging, no mid barrier).
// Blocks [NBLK, NBLK+NPAIR_BLK): gather path, 16 sampled pairs per wave, one shot.
// Frag layouts (HW-verified): A/B = X[idx=lane&15][k=(lane>>4)*8+j];
// C/D row=(lane>>4)*4+reg, col=lane&15.
__global__ __launch_bounds__(256) void fused_kernel(const unsigned* __restrict__ W16,
                                                    const float* __restrict__ sq,
                                                    const float* __restrict__ pij,
                                                    const int* __restrict__ ii,
                                                    const int* __restrict__ jj,
                                                    int nb,
                                                    float* __restrict__ partA,
                                                    float* __restrict__ a1p,
                                                    float* __restrict__ a3p) {
    __shared__ float red[8];
    int z = blockIdx.x;
    int t = threadIdx.x, w = t >> 6, lane = t & 63;

    if (z < NBLK) {
        // ---------------- pairwise MFMA path ----------------
        int by = (int)((129.0 - sqrt(16641.0 - 8.0 * (double)z)) * 0.5);
        while (by * NT2 - by * (by - 1) / 2 > z) --by;
        while ((by + 1) * NT2 - (by + 1) * by / 2 <= z) ++by;
        int bx = by + (z - (by * NT2 - by * (by - 1) / 2));

        int wm = w >> 1, wn = w & 1, quad = lane >> 4, l15 = lane & 15;
        int a0 = by * TILE, b0 = bx * TILE;

        float4 base1[4];                 // 1 + sq[arow + tm*16 + 0..3]
        float  sqb[4];
        {
            int arow = a0 + wm * 64 + quad * 4;
            #pragma unroll
            for (int tm = 0; tm < 4; ++tm) {
                float4 v = *(const float4*)(sq + arow + tm * 16);
                base1[tm] = (float4){1.0f + v.x, 1.0f + v.y, 1.0f + v.z, 1.0f + v.w};
            }
            int bcol = b0 + wn * 64 + l15;
            #pragma unroll
            for (int tn = 0; tn < 4; ++tn) sqb[tn] = sq[bcol + tn * 16];
        }

        f32x4 acc[4][4];
        #pragma unroll
        for (int i = 0; i < 4; ++i)
            #pragma unroll
            for (int j = 0; j < 4; ++j) acc[i][j] = (f32x4){0.f, 0.f, 0.f, 0.f};

        const unsigned* Arow = W16 + (a0 + wm * 64 + l15) * 32;   // row pitch 32 dwords
        const unsigned* Brow = W16 + (b0 + wn * 64 + l15) * 32;
        #pragma unroll
        for (int h = 0; h < 2; ++h) {    // two K=32 halves; frag = 4 dwords, 16B-aligned
            bf16x8 af[4], bfr[4];
            #pragma unroll
            for (int tm = 0; tm < 4; ++tm)
                af[tm] = *(const bf16x8*)(Arow + tm * 16 * 32 + h * 16 + quad * 4);
            #pragma unroll
            for (int tn = 0; tn < 4; ++tn)
                bfr[tn] = *(const bf16x8*)(Brow + tn * 16 * 32 + h * 16 + quad * 4);
            #pragma unroll
            for (int tm = 0; tm < 4; ++tm)
                #pragma unroll
                for (int tn = 0; tn < 4; ++tn)
                    acc[tm][tn] = __builtin_amdgcn_mfma_f32_16x16x32_bf16(af[tm], bfr[tn],
                                                                          acc[tm][tn], 0, 0, 0);
        }

        float ssum = 0.f;
        if (bx > by) {
            #pragma unroll
            for (int tn = 0; tn < 4; ++tn) {
                float c0 = sqb[tn];
                #pragma unroll
                for (int tm = 0; tm < 4; ++tm) {
                    ssum += __builtin_amdgcn_rcpf(fmaf(acc[tm][tn][0], -2.0f, base1[tm].x + c0));
                    ssum += __builtin_amdgcn_rcpf(fmaf(acc[tm][tn][1], -2.0f, base1[tm].y + c0));
                    ssum += __builtin_amdgcn_rcpf(fmaf(acc[tm][tn][2], -2.0f, base1[tm].z + c0));
                    ssum += __builtin_amdgcn_rcpf(fmaf(acc[tm][tn][3], -2.0f, base1[tm].w + c0));
                }
            }
        } else {                         // diagonal block: strictly-upper only
            int quad4 = quad * 4;
            #pragma unroll
            for (int tn = 0; tn < 4; ++tn) {
                int cl = wn * 64 + tn * 16 + l15;
                float c0 = sqb[tn];
                float b4[4] = {0, 0, 0, 0};
                #pragma unroll
                for (int tm = 0; tm < 4; ++tm) {
                    b4[0] = base1[tm].x; b4[1] = base1[tm].y;
                    b4[2] = base1[tm].z; b4[3] = base1[tm].w;
                    #pragma unroll
                    for (int r = 0; r < 4; ++r) {
                        int rl = wm * 64 + tm * 16 + quad4 + r;
                        float inv = __builtin_amdgcn_rcpf(fmaf(acc[tm][tn][r], -2.0f, b4[r] + c0));
                        ssum += (cl > rl) ? inv : 0.f;
                    }
                }
            }
        }
        #pragma unroll
        for (int m = 32; m >= 1; m >>= 1) ssum += __shfl_xor(ssum, m, 64);
        if (lane == 0) red[w] = ssum;
        __syncthreads();
        if (t == 0) partA[z] = red[0] + red[1] + red[2] + red[3];
    } else {
        // ---------------- sampled-pair gather path ----------------
        int pb = z - NBLK;
        int p0 = (pb * 4 + w) * 16;      // this wave's 16 pairs
        float a1 = 0.f, a3 = 0.f;
        if (p0 < nb) {
            int g = lane >> 3;           // pair slot (0..7)
            int s = lane & 7;            // 16B chunk slot within the 128B row
            int  pA = p0 + g,        pB = p0 + 8 + g;
            bool okA = pA < nb,      okB = pB < nb;
            int  cA = okA ? pA : 0,  cB = okB ? pB : 0;
            int   iA = ii[cA], jA = jj[cA];
            int   iB = ii[cB], jB = jj[cB];
            float pvA = pij[cA], pvB = pij[cB];
            uint4 xiA = *(const uint4*)(W16 + iA * 32 + s * 4);
            uint4 xjA = *(const uint4*)(W16 + jA * 32 + s * 4);
            uint4 xiB = *(const uint4*)(W16 + iB * 32 + s * 4);
            uint4 xjB = *(const uint4*)(W16 + jB * 32 + s * 4);
            float sA = sq[iA] + sq[jA];
            float sB = sq[iB] + sq[jB];

            float dA, dB;                // per-lane partial dot(xi, xj)
            {
                dA = bflo(xiA.x) * bflo(xjA.x);
                dA = fmaf(bfhi(xiA.x), bfhi(xjA.x), dA);
                dA = fmaf(bflo(xiA.y), bflo(xjA.y), dA);
                dA = fmaf(bfhi(xiA.y), bfhi(xjA.y), dA);
                dA = fmaf(bflo(xiA.z), bflo(xjA.z), dA);
                dA = fmaf(bfhi(xiA.z), bfhi(xjA.z), dA);
                dA = fmaf(bflo(xiA.w), bflo(xjA.w), dA);
                dA = fmaf(bfhi(xiA.w), bfhi(xjA.w), dA);
            }
            {
                dB = bflo(xiB.x) * bflo(xjB.x);
                dB = fmaf(bfhi(xiB.x), bfhi(xjB.x), dB);
                dB = fmaf(bflo(xiB.y), bflo(xjB.y), dB);
                dB = fmaf(bfhi(xiB.y), bfhi(xjB.y), dB);
                dB = fmaf(bflo(xiB.z), bflo(xjB.z), dB);
                dB = fmaf(bfhi(xiB.z), bfhi(xjB.z), dB);
                dB = fmaf(bflo(xiB.w), bflo(xjB.w), dB);
                dB = fmaf(bfhi(xiB.w), bfhi(xjB.w), dB);
            }
            #pragma unroll
            for (int m = 1; m <= 4; m <<= 1) {
                dA += __shfl_xor(dA, m, 64);
                dB += __shfl_xor(dB, m, 64);
            }
            float vA = fmaf(dA, -2.0f, sA);              // ||xi-xj||^2 (>=0 up to rounding)
            float vB = fmaf(dB, -2.0f, sB);
            float tA = pvA * __logf(pvA * ((float)NDIM + vA));
            float tB = pvB * __logf(pvB * ((float)NDIM + vB));
            a1 += okA ? tA : 0.f;  a3 += okA ? pvA : 0.f;
            a1 += okB ? tB : 0.f;  a3 += okB ? pvB : 0.f;
        }
        #pragma unroll
        for (int m = 32; m >= 1; m >>= 1) {
            a1 += __shfl_xor(a1, m, 64);
            a3 += __shfl_xor(a3, m, 64);
        }
        if (lane == 0) { red[w] = a1 * 0.125f; red[4 + w] = a3 * 0.125f; }  // 8x lane redundancy
        __syncthreads();
        if (t == 0) {
            a1p[pb] = red[0] + red[1] + red[2] + red[3];
            a3p[pb] = red[4] + red[5] + red[6] + red[7];
        }
    }
}

__global__ __launch_bounds__(256) void final_kernel(const float* __restrict__ partA,
                                                    const float* __restrict__ a1p,
                                                    const float* __restrict__ a3p,
                                                    float* __restrict__ out) {
    __shared__ double r1[256], r2[256], r3[256];
    int t = threadIdx.x;
    double dpart = 0.0, d1 = 0.0, d3 = 0.0;
    for (int k = t; k < NBLK; k += 256) dpart += (double)partA[k];
    for (int k = t; k < NPAIR_BLK; k += 256) { d1 += (double)a1p[k]; d3 += (double)a3p[k]; }
    r1[t] = dpart; r2[t] = d1; r3[t] = d3;
    __syncthreads();
    for (int s = 128; s >= 1; s >>= 1) {
        if (t < s) { r1[t] += r1[t + s]; r2[t] += r2[t + s]; r3[t] += r3[t + s]; }
        __syncthreads();
    }
    if (t == 0) {
        double part = 2.0 * r1[0];                 // sum over a<b, doubled; diagonal cancels -n
        out[0] = (float)(r2[0] + r3[0] * log(part));
    }
}

extern "C" void kernel_launch(void* const* d_in, const int* in_sizes, int n_in,
                              void* d_out, int out_size, void* d_ws, size_t ws_size,
                              hipStream_t stream) {
    const float* pij = (const float*)d_in[0];
    const int*   ii  = (const int*)d_in[1];
    const int*   jj  = (const int*)d_in[2];
    const float* W   = (const float*)d_in[3];
    float* out = (float*)d_out;
    float* ws  = (float*)d_ws;

    unsigned* W16   = (unsigned*)ws + WS_W16;
    float*    sqv   = ws + WS_SQ;
    float*    partA = ws + WS_PARTA;
    float*    a1p   = ws + WS_A1P;
    float*    a3p   = ws + WS_A3P;

    int nb = in_sizes[0];   // number of sampled pairs (B)

    prep_kernel<<<NPOINTS / 4, 256, 0, stream>>>(W, sqv, W16);
    fused_kernel<<<NBLK + NPAIR_BLK, 256, 0, stream>>>(W16, sqv, pij, ii, jj, nb,
                                                       partA, a1p, a3p);
    final_kernel<<<1, 256, 0, stream>>>(partA, a1p, a3p, out);
}

// Round 5
// 110.874 us; speedup vs baseline: 1.1018x; 1.1018x over previous
//
#include <hip/hip_runtime.h>
#include <math.h>

// Problem constants (fixed by the reference file)
#define NPOINTS   8192
#define NDIM      64
#define TILE      128          // pairwise output tile per block
#define NT2       64           // NPOINTS / TILE
#define NBLK      2080         // NT2*(NT2+1)/2 triangle blocks
#define NPAIRB    1040         // pair-role blocks (interleaved 1-in-3)
#define NPW       (NPAIRB * 4) // pair waves
#define GRID      3120         // 2080 MFMA + 1040 pair, interleaved z%3

// ws dword/float layout:
//  [0, 262144)        W16   : W as bf16, packed 2/dword (8192 rows x 32 dwords)
//  [262144, 270336)   sq    : row squared norms (fp32 exact)
//  [270336, 272416)   partA : per-block partials of sum 1/(1+d2) over a<b  (2080)
//  [272416, 273456)   a1p   : per-block partials of sum pij*log(pij*(64+d2))  (1040)
//  [273456, 274496)   a3p   : per-block partials of sum pij                   (1040)
#define WS_W16   0
#define WS_SQ    262144
#define WS_PARTA 270336
#define WS_A1P   272416
#define WS_A3P   273456

typedef __attribute__((ext_vector_type(8))) short bf16x8;   // 8 bf16 = 4 VGPRs (MFMA A/B frag)
typedef __attribute__((ext_vector_type(4))) float f32x4;    // MFMA C/D frag

__device__ inline unsigned short f2bf(float f) {            // fp32 -> bf16 RNE
    unsigned u = __float_as_uint(f);
    u += 0x7FFFu + ((u >> 16) & 1u);
    return (unsigned short)(u >> 16);
}
__device__ inline float bflo(unsigned u) { return __uint_as_float(u << 16); }
__device__ inline float bfhi(unsigned u) { return __uint_as_float(u & 0xFFFF0000u); }

// One wave per row: exact fp32 row norm + bf16 conversion of W (packed 2/dword).
__global__ __launch_bounds__(256) void prep_kernel(const float* __restrict__ W,
                                                   float* __restrict__ sq,
                                                   unsigned* __restrict__ W16) {
    int wid  = (blockIdx.x * 256 + threadIdx.x) >> 6;   // row
    int lane = threadIdx.x & 63;
    float v = W[wid * NDIM + lane];
    float s = v * v;
    #pragma unroll
    for (int m = 32; m >= 1; m >>= 1) s += __shfl_xor(s, m, 64);
    if (lane == 0) sq[wid] = s;
    unsigned bf   = f2bf(v);
    unsigned peer = (unsigned)__shfl_xor((int)bf, 1, 64);
    if ((lane & 1) == 0)                                 // even lane packs (elem l | elem l+1)
        W16[wid * 32 + (lane >> 1)] = (bf & 0xFFFFu) | (peer << 16);
}

// Fused main kernel, roles interleaved mod 3 so both kinds are co-resident:
//   z%3 < 2  -> MFMA tile m = (z/3)*2 + z%3   (exactly 2080 triangle tiles)
//   z%3 == 2 -> pair block pb = z/3           (1040 blocks, looped gather path)
// MFMA frag layouts (HW-verified): A/B = X[idx=lane&15][k=(lane>>4)*8+j];
// C/D row=(lane>>4)*4+reg, col=lane&15.
__global__ __launch_bounds__(256) void fused_kernel(const unsigned* __restrict__ W16,
                                                    const float* __restrict__ sq,
                                                    const float* __restrict__ pij,
                                                    const int* __restrict__ ii,
                                                    const int* __restrict__ jj,
                                                    int nb,
                                                    float* __restrict__ partA,
                                                    float* __restrict__ a1p,
                                                    float* __restrict__ a3p) {
    __shared__ float red[8];
    int zb = blockIdx.x;
    int t = threadIdx.x, w = t >> 6, lane = t & 63;

    if ((zb % 3) < 2) {
        // ---------------- pairwise MFMA path ----------------
        int z = (zb / 3) * 2 + (zb % 3);     // triangle tile id in [0, 2080)
        int by = (int)((129.0 - sqrt(16641.0 - 8.0 * (double)z)) * 0.5);
        while (by * NT2 - by * (by - 1) / 2 > z) --by;
        while ((by + 1) * NT2 - (by + 1) * by / 2 <= z) ++by;
        int bx = by + (z - (by * NT2 - by * (by - 1) / 2));

        int wm = w >> 1, wn = w & 1, quad = lane >> 4, l15 = lane & 15;
        int a0 = by * TILE, b0 = bx * TILE;

        float4 base1[4];                 // 1 + sq[arow + tm*16 + 0..3]
        float  sqb[4];
        {
            int arow = a0 + wm * 64 + quad * 4;
            #pragma unroll
            for (int tm = 0; tm < 4; ++tm) {
                float4 v = *(const float4*)(sq + arow + tm * 16);
                base1[tm] = (float4){1.0f + v.x, 1.0f + v.y, 1.0f + v.z, 1.0f + v.w};
            }
            int bcol = b0 + wn * 64 + l15;
            #pragma unroll
            for (int tn = 0; tn < 4; ++tn) sqb[tn] = sq[bcol + tn * 16];
        }

        f32x4 acc[4][4];
        #pragma unroll
        for (int i = 0; i < 4; ++i)
            #pragma unroll
            for (int j = 0; j < 4; ++j) acc[i][j] = (f32x4){0.f, 0.f, 0.f, 0.f};

        const unsigned* Arow = W16 + (a0 + wm * 64 + l15) * 32;   // row pitch 32 dwords
        const unsigned* Brow = W16 + (b0 + wn * 64 + l15) * 32;
        #pragma unroll
        for (int h = 0; h < 2; ++h) {    // two K=32 halves; frag = 4 dwords, 16B-aligned
            bf16x8 af[4], bfr[4];
            #pragma unroll
            for (int tm = 0; tm < 4; ++tm)
                af[tm] = *(const bf16x8*)(Arow + tm * 16 * 32 + h * 16 + quad * 4);
            #pragma unroll
            for (int tn = 0; tn < 4; ++tn)
                bfr[tn] = *(const bf16x8*)(Brow + tn * 16 * 32 + h * 16 + quad * 4);
            #pragma unroll
            for (int tm = 0; tm < 4; ++tm)
                #pragma unroll
                for (int tn = 0; tn < 4; ++tn)
                    acc[tm][tn] = __builtin_amdgcn_mfma_f32_16x16x32_bf16(af[tm], bfr[tn],
                                                                          acc[tm][tn], 0, 0, 0);
        }

        float ssum = 0.f;
        if (bx > by) {
            #pragma unroll
            for (int tn = 0; tn < 4; ++tn) {
                float c0 = sqb[tn];
                #pragma unroll
                for (int tm = 0; tm < 4; ++tm) {
                    ssum += __builtin_amdgcn_rcpf(fmaf(acc[tm][tn][0], -2.0f, base1[tm].x + c0));
                    ssum += __builtin_amdgcn_rcpf(fmaf(acc[tm][tn][1], -2.0f, base1[tm].y + c0));
                    ssum += __builtin_amdgcn_rcpf(fmaf(acc[tm][tn][2], -2.0f, base1[tm].z + c0));
                    ssum += __builtin_amdgcn_rcpf(fmaf(acc[tm][tn][3], -2.0f, base1[tm].w + c0));
                }
            }
        } else {                         // diagonal block: strictly-upper only
            int quad4 = quad * 4;
            #pragma unroll
            for (int tn = 0; tn < 4; ++tn) {
                int cl = wn * 64 + tn * 16 + l15;
                float c0 = sqb[tn];
                float b4[4];
                #pragma unroll
                for (int tm = 0; tm < 4; ++tm) {
                    b4[0] = base1[tm].x; b4[1] = base1[tm].y;
                    b4[2] = base1[tm].z; b4[3] = base1[tm].w;
                    #pragma unroll
                    for (int r = 0; r < 4; ++r) {
                        int rl = wm * 64 + tm * 16 + quad4 + r;
                        float inv = __builtin_amdgcn_rcpf(fmaf(acc[tm][tn][r], -2.0f, b4[r] + c0));
                        ssum += (cl > rl) ? inv : 0.f;
                    }
                }
            }
        }
        #pragma unroll
        for (int m = 32; m >= 1; m >>= 1) ssum += __shfl_xor(ssum, m, 64);
        if (lane == 0) red[w] = ssum;
        __syncthreads();
        if (t == 0) partA[z] = red[0] + red[1] + red[2] + red[3];
    } else {
        // ---------------- sampled-pair gather path (looped, pipelined) ----------------
        int pb = zb / 3;                 // [0, 1040)
        int pw = pb * 4 + w;             // pair-wave id in [0, NPW)
        int g = lane >> 3;               // pair slot (0..7)
        int s = lane & 7;                // 16B chunk slot within the 128B row
        float a1 = 0.f, a3 = 0.f;

        #pragma unroll 2
        for (int p0 = pw * 16; p0 < nb; p0 += NPW * 16) {
            int  pA = p0 + g,        pB = p0 + 8 + g;
            bool okA = pA < nb,      okB = pB < nb;
            int  cA = okA ? pA : 0,  cB = okB ? pB : 0;
            int   iA = ii[cA], jA = jj[cA];
            int   iB = ii[cB], jB = jj[cB];
            float pvA = pij[cA], pvB = pij[cB];
            uint4 xiA = *(const uint4*)(W16 + iA * 32 + s * 4);
            uint4 xjA = *(const uint4*)(W16 + jA * 32 + s * 4);
            uint4 xiB = *(const uint4*)(W16 + iB * 32 + s * 4);
            uint4 xjB = *(const uint4*)(W16 + jB * 32 + s * 4);
            float sA = sq[iA] + sq[jA];
            float sB = sq[iB] + sq[jB];

            float dA, dB;                // per-lane partial dot(xi, xj)
            {
                dA = bflo(xiA.x) * bflo(xjA.x);
                dA = fmaf(bfhi(xiA.x), bfhi(xjA.x), dA);
                dA = fmaf(bflo(xiA.y), bflo(xjA.y), dA);
                dA = fmaf(bfhi(xiA.y), bfhi(xjA.y), dA);
                dA = fmaf(bflo(xiA.z), bflo(xjA.z), dA);
                dA = fmaf(bfhi(xiA.z), bfhi(xjA.z), dA);
                dA = fmaf(bflo(xiA.w), bflo(xjA.w), dA);
                dA = fmaf(bfhi(xiA.w), bfhi(xjA.w), dA);
            }
            {
                dB = bflo(xiB.x) * bflo(xjB.x);
                dB = fmaf(bfhi(xiB.x), bfhi(xjB.x), dB);
                dB = fmaf(bflo(xiB.y), bflo(xjB.y), dB);
                dB = fmaf(bfhi(xiB.y), bfhi(xjB.y), dB);
                dB = fmaf(bflo(xiB.z), bflo(xjB.z), dB);
                dB = fmaf(bfhi(xiB.z), bfhi(xjB.z), dB);
                dB = fmaf(bflo(xiB.w), bflo(xjB.w), dB);
                dB = fmaf(bfhi(xiB.w), bfhi(xjB.w), dB);
            }
            #pragma unroll
            for (int m = 1; m <= 4; m <<= 1) {
                dA += __shfl_xor(dA, m, 64);
                dB += __shfl_xor(dB, m, 64);
            }
            float vA = fmaf(dA, -2.0f, sA);              // ||xi-xj||^2
            float vB = fmaf(dB, -2.0f, sB);
            float tA = pvA * __logf(pvA * ((float)NDIM + vA));
            float tB = pvB * __logf(pvB * ((float)NDIM + vB));
            a1 += okA ? tA : 0.f;  a3 += okA ? pvA : 0.f;
            a1 += okB ? tB : 0.f;  a3 += okB ? pvB : 0.f;
        }
        #pragma unroll
        for (int m = 32; m >= 1; m >>= 1) {
            a1 += __shfl_xor(a1, m, 64);
            a3 += __shfl_xor(a3, m, 64);
        }
        if (lane == 0) { red[w] = a1 * 0.125f; red[4 + w] = a3 * 0.125f; }  // 8x lane redundancy
        __syncthreads();
        if (t == 0) {
            a1p[pb] = red[0] + red[1] + red[2] + red[3];
            a3p[pb] = red[4] + red[5] + red[6] + red[7];
        }
    }
}

__global__ __launch_bounds__(256) void final_kernel(const float* __restrict__ partA,
                                                    const float* __restrict__ a1p,
                                                    const float* __restrict__ a3p,
                                                    float* __restrict__ out) {
    __shared__ double r1[256], r2[256], r3[256];
    int t = threadIdx.x;
    double dpart = 0.0, d1 = 0.0, d3 = 0.0;
    for (int k = t; k < NBLK; k += 256) dpart += (double)partA[k];
    for (int k = t; k < NPAIRB; k += 256) { d1 += (double)a1p[k]; d3 += (double)a3p[k]; }
    r1[t] = dpart; r2[t] = d1; r3[t] = d3;
    __syncthreads();
    for (int s = 128; s >= 1; s >>= 1) {
        if (t < s) { r1[t] += r1[t + s]; r2[t] += r2[t + s]; r3[t] += r3[t + s]; }
        __syncthreads();
    }
    if (t == 0) {
        double part = 2.0 * r1[0];                 // sum over a<b, doubled; diagonal cancels -n
        out[0] = (float)(r2[0] + r3[0] * log(part));
    }
}

extern "C" void kernel_launch(void* const* d_in, const int* in_sizes, int n_in,
                              void* d_out, int out_size, void* d_ws, size_t ws_size,
                              hipStream_t stream) {
    const float* pij = (const float*)d_in[0];
    const int*   ii  = (const int*)d_in[1];
    const int*   jj  = (const int*)d_in[2];
    const float* W   = (const float*)d_in[3];
    float* out = (float*)d_out;
    float* ws  = (float*)d_ws;

    unsigned* W16   = (unsigned*)ws + WS_W16;
    float*    sqv   = ws + WS_SQ;
    float*    partA = ws + WS_PARTA;
    float*    a1p   = ws + WS_A1P;
    float*    a3p   = ws + WS_A3P;

    int nb = in_sizes[0];   // number of sampled pairs (B)

    prep_kernel<<<NPOINTS / 4, 256, 0, stream>>>(W, sqv, W16);
    fused_kernel<<<GRID, 256, 0, stream>>>(W16, sqv, pij, ii, jj, nb, partA, a1p, a3p);
    final_kernel<<<1, 256, 0, stream>>>(partA, a1p, a3p, out);
}